// Round 2
// baseline (119.053 us; speedup 1.0000x reference)
//
#include <hip/hip_runtime.h>
#include <hip/hip_bf16.h>

#define N_IN   256
#define N_HID  128
#define N_ELEM 5
#define BM     128   // atoms per block (4 waves x 32 atoms)

typedef __attribute__((ext_vector_type(8))) short  short8;
typedef __attribute__((ext_vector_type(4))) short  short4v;
typedef __attribute__((ext_vector_type(4))) float  float4v;

__device__ __forceinline__ int expert_of(int z) {
    // 1->0 (H), 6->1 (C), 7->2 (N), 8->3 (O), 16->4 (S)
    return (z == 1) ? 0 : (z == 6) ? 1 : (z == 7) ? 2 : (z == 8) ? 3 : 4;
}

// fp32 -> bf16 round-to-nearest-even, as raw short
__device__ __forceinline__ short f2bf(float f) {
    union { float f; unsigned u; } c; c.f = f;
    unsigned r = (c.u + 0x7fffu + ((c.u >> 16) & 1u)) >> 16;
    return (short)r;
}

// ---------------- prep: W1 fp32 -> bf16 (same [e][hid][k] layout) --------------
__global__ void prep_w_kernel(const float* __restrict__ W1, short* __restrict__ W1b, int n) {
    int i = (blockIdx.x * blockDim.x + threadIdx.x) * 4;
    if (i >= n) return;
    float4v f = *(const float4v*)(W1 + i);
    short4v s;
    s[0] = f2bf(f[0]); s[1] = f2bf(f[1]); s[2] = f2bf(f[2]); s[3] = f2bf(f[3]);
    *(short4v*)(W1b + i) = s;
}

// ---------------- histogram ----------------------------------------------------
__global__ void hist_kernel(const int* __restrict__ z, int n, int* __restrict__ counts) {
    __shared__ int cnt[N_ELEM];
    if (threadIdx.x < N_ELEM) cnt[threadIdx.x] = 0;
    __syncthreads();
    int i = blockIdx.x * blockDim.x + threadIdx.x;
    if (i < n) atomicAdd(&cnt[expert_of(z[i])], 1);
    __syncthreads();
    if (threadIdx.x < N_ELEM && cnt[threadIdx.x]) atomicAdd(&counts[threadIdx.x], cnt[threadIdx.x]);
}

// ---------------- tile table + cursor init ------------------------------------
__global__ void build_tiles_kernel(const int* __restrict__ counts, int* __restrict__ cursor,
                                   int* __restrict__ nTiles, int* __restrict__ tileE,
                                   int* __restrict__ tileStart, int* __restrict__ tileRows) {
    __shared__ int soff[N_ELEM], scnt[N_ELEM], stp[N_ELEM + 1];
    if (threadIdx.x == 0) {
        int o = 0, tp = 0;
        for (int e = 0; e < N_ELEM; ++e) {
            int c = counts[e];
            scnt[e] = c; soff[e] = o; cursor[e] = o; stp[e] = tp;
            o += c; tp += (c + BM - 1) / BM;
        }
        stp[N_ELEM] = tp;
        nTiles[0] = tp;
    }
    __syncthreads();
    int total = stp[N_ELEM];
    for (int t = threadIdx.x; t < total; t += blockDim.x) {
        int e = 0;
        while (e < N_ELEM - 1 && t >= stp[e + 1]) ++e;
        int i = t - stp[e];
        tileE[t] = e;
        tileStart[t] = soff[e] + i * BM;
        tileRows[t] = min(BM, scnt[e] - i * BM);
    }
}

// ---------------- scatter atoms into expert-sorted perm ------------------------
__global__ void scatter_kernel(const int* __restrict__ z, int n,
                               int* __restrict__ cursor, int* __restrict__ perm) {
    __shared__ int cnt[N_ELEM], cur[N_ELEM], base[N_ELEM];
    int tid = threadIdx.x;
    if (tid < N_ELEM) { cnt[tid] = 0; cur[tid] = 0; }
    __syncthreads();
    int i = blockIdx.x * blockDim.x + tid;
    int e = -1;
    if (i < n) { e = expert_of(z[i]); atomicAdd(&cnt[e], 1); }
    __syncthreads();
    if (tid < N_ELEM) base[tid] = cnt[tid] ? atomicAdd(&cursor[tid], cnt[tid]) : 0;
    __syncthreads();
    if (e >= 0) {
        int r = atomicAdd(&cur[e], 1);
        perm[base[e] + r] = i;
    }
}

// ---------------- fused grouped GEMM, barrier-free -----------------------------
// Wave w of each block owns atoms [w*32, w*32+32) of the tile: 2 M-tiles x
// all 8 N-tiles. A from global X (fp32->bf16 in reg), B from L2-resident W1b.
// Layer 2 fully in-register via shfl_xor reduce. No LDS, no __syncthreads.
__launch_bounds__(256, 3)
__global__ void mlp_kernel(const float* __restrict__ X, const short* __restrict__ W1b,
                           const float* __restrict__ B1, const float* __restrict__ W2,
                           const float* __restrict__ B2, const int* __restrict__ perm,
                           const int* __restrict__ nTiles, const int* __restrict__ tileE,
                           const int* __restrict__ tileStart, const int* __restrict__ tileRows,
                           float* __restrict__ out) {
    int t = blockIdx.x;
    if (t >= nTiles[0]) return;
    int e = tileE[t], rs = tileStart[t], rows = tileRows[t];

    int lane = threadIdx.x & 63;
    int w    = threadIdx.x >> 6;
    int r0   = w * 32;                    // wave's first row within tile
    if (r0 >= rows) return;               // no barriers -> safe early exit

    int am = lane & 15;                   // A-row / C-col sublane
    int g  = lane >> 4;                   // k-group 0..3

    const short* Wb = W1b + e * (N_HID * N_IN);

    // gather atom ids for this wave's 32 rows (lane&15 -> row within M-tile)
    int gid[2];
#pragma unroll
    for (int mi = 0; mi < 2; ++mi) {
        int rl = r0 + mi * 16 + am;
        gid[mi] = perm[rs + min(rl, rows - 1)];
    }
    const float* xr0 = X + (long)gid[0] * N_IN + g * 8;
    const float* xr1 = X + (long)gid[1] * N_IN + g * 8;

    float4v acc[2][8] = {};
#pragma unroll
    for (int kk = 0; kk < 8; ++kk) {
        // A fragments: row = lane&15, k = kk*32 + g*8 + j  (128B/row coalesced)
        short8 a0, a1;
        {
            float4v f0 = *(const float4v*)(xr0 + kk * 32);
            float4v f1 = *(const float4v*)(xr0 + kk * 32 + 4);
            a0[0] = f2bf(f0[0]); a0[1] = f2bf(f0[1]); a0[2] = f2bf(f0[2]); a0[3] = f2bf(f0[3]);
            a0[4] = f2bf(f1[0]); a0[5] = f2bf(f1[1]); a0[6] = f2bf(f1[2]); a0[7] = f2bf(f1[3]);
            float4v g0 = *(const float4v*)(xr1 + kk * 32);
            float4v g1 = *(const float4v*)(xr1 + kk * 32 + 4);
            a1[0] = f2bf(g0[0]); a1[1] = f2bf(g0[1]); a1[2] = f2bf(g0[2]); a1[3] = f2bf(g0[3]);
            a1[4] = f2bf(g1[0]); a1[5] = f2bf(g1[1]); a1[6] = f2bf(g1[2]); a1[7] = f2bf(g1[3]);
        }
#pragma unroll
        for (int n = 0; n < 8; ++n) {
            short8 b = *(const short8*)(Wb + (n * 16 + am) * N_IN + kk * 32 + g * 8);
            acc[0][n] = __builtin_amdgcn_mfma_f32_16x16x32_bf16(a0, b, acc[0][n], 0, 0, 0);
            acc[1][n] = __builtin_amdgcn_mfma_f32_16x16x32_bf16(a1, b, acc[1][n], 0, 0, 0);
        }
    }

    // per-lane slice of b1 / w2 (col = n*16 + am)
    float b1c[8], w2c[8];
#pragma unroll
    for (int n = 0; n < 8; ++n) {
        int c = n * 16 + am;
        b1c[n] = B1[e * N_HID + c];
        w2c[n] = W2[e * N_HID + c];
    }
    float b2v = B2[e];

    // bias + silu + layer-2 dot, all in registers.
    // C layout: col = lane&15 (hidden), row = g*4 + reg. Reduce over lane&15.
#pragma unroll
    for (int mi = 0; mi < 2; ++mi) {
        float part0 = 0, part1 = 0, part2 = 0, part3 = 0;
#pragma unroll
        for (int n = 0; n < 8; ++n) {
            float v0 = acc[mi][n][0] + b1c[n]; v0 = v0 / (1.0f + __expf(-v0));
            float v1 = acc[mi][n][1] + b1c[n]; v1 = v1 / (1.0f + __expf(-v1));
            float v2 = acc[mi][n][2] + b1c[n]; v2 = v2 / (1.0f + __expf(-v2));
            float v3 = acc[mi][n][3] + b1c[n]; v3 = v3 / (1.0f + __expf(-v3));
            part0 += v0 * w2c[n]; part1 += v1 * w2c[n];
            part2 += v2 * w2c[n]; part3 += v3 * w2c[n];
        }
#pragma unroll
        for (int s = 1; s <= 8; s <<= 1) {
            part0 += __shfl_xor(part0, s, 64);
            part1 += __shfl_xor(part1, s, 64);
            part2 += __shfl_xor(part2, s, 64);
            part3 += __shfl_xor(part3, s, 64);
        }
        // lanes with am<4 write rows r0 + mi*16 + g*4 + am
        int rr = am & 3;
        float val = part0;
        if (rr == 1) val = part1;
        else if (rr == 2) val = part2;
        else if (rr == 3) val = part3;
        int tgt = __shfl(gid[mi], g * 4 + rr, 64);   // lane (g*4+rr) holds that row's gid
        int rl  = r0 + mi * 16 + g * 4 + rr;
        if (am < 4 && rl < rows) out[tgt] = val + b2v;
    }
}

// ---------------- launch -------------------------------------------------------
extern "C" void kernel_launch(void* const* d_in, const int* in_sizes, int n_in,
                              void* d_out, int out_size, void* d_ws, size_t ws_size,
                              hipStream_t stream) {
    const int*   z  = (const int*)  d_in[0];
    const float* X  = (const float*)d_in[1];
    const float* W1 = (const float*)d_in[2];
    const float* B1 = (const float*)d_in[3];
    const float* W2 = (const float*)d_in[4];
    const float* B2 = (const float*)d_in[5];
    float* out = (float*)d_out;
    int nAtoms = in_sizes[0];

    char* ws = (char*)d_ws;
    size_t off = 0;
    short* W1b = (short*)(ws + off); off += (size_t)N_ELEM * N_HID * N_IN * 2;  // 327680
    int* perm    = (int*)(ws + off); off += (size_t)nAtoms * 4;
    int* counts  = (int*)(ws + off); off += 32;
    int* cursor  = (int*)(ws + off); off += 32;
    int* nTiles  = (int*)(ws + off); off += 32;
    int maxTiles = (nAtoms + BM - 1) / BM + N_ELEM;
    int* tileE     = (int*)(ws + off); off += (size_t)maxTiles * 4;
    int* tileStart = (int*)(ws + off); off += (size_t)maxTiles * 4;
    int* tileRows  = (int*)(ws + off); off += (size_t)maxTiles * 4;

    hipMemsetAsync(counts, 0, 32, stream);

    int wElems = N_ELEM * N_HID * N_IN;
    prep_w_kernel<<<(wElems / 4 + 255) / 256, 256, 0, stream>>>(W1, W1b, wElems);

    int hb = (nAtoms + 255) / 256;
    hist_kernel<<<hb, 256, 0, stream>>>(z, nAtoms, counts);
    build_tiles_kernel<<<1, 256, 0, stream>>>(counts, cursor, nTiles, tileE, tileStart, tileRows);
    scatter_kernel<<<hb, 256, 0, stream>>>(z, nAtoms, cursor, perm);
    mlp_kernel<<<maxTiles, 256, 0, stream>>>(X, W1b, B1, W2, B2, perm,
                                             nTiles, tileE, tileStart, tileRows, out);
}